// Round 1
// baseline (73.499 us; speedup 1.0000x reference)
//
#include <hip/hip_runtime.h>
#include <math.h>

#define THREADS 512
#define MHALF 8192      // complex FFT length (N/2)
#define NREAL 16384
#define FBINS 8193
#define MIN_IDX 364     // argmin |f - 40/60|, exact fp32 (f[k]=k*15/8192 is exact)
#define MAX_IDX 2276    // argmin |f - 250/60|, exact fp32

__device__ __forceinline__ int br13(int x) {
    return (int)(__brev((unsigned)x) >> 19);
}

// One block per row. LDS: exactly 64 KiB (re+im), 2 blocks/CU.
__global__ __launch_bounds__(THREADS, 4)
void negsnr_row_kernel(const float* __restrict__ x,
                       const float* __restrict__ targets,
                       float* __restrict__ snr_out)
{
    __shared__ float re[MHALF];
    __shared__ float im[MHALF];
    const int row  = blockIdx.x;
    const int tid  = threadIdx.x;
    const int lane = tid & 63;
    const int wave = tid >> 6;

    // ---- Phase 0: ref_idx = argmin_k |k*step - t_hz|, exact fp32 replication ----
    // key = (bits(|d|) << 32) | k : min over keys == argmin with first-index ties
    const float step = 15.0f / 8192.0f;           // exact in fp32
    const float t_hz = targets[row] / 60.0f;
    unsigned long long key = ~0ull;
    for (int k = tid; k < FBINS; k += THREADS) {
        float d = fabsf((float)k * step - t_hz);
        unsigned long long cand =
            ((unsigned long long)__float_as_uint(d) << 32) | (unsigned)k;
        if (cand < key) key = cand;
    }
    #pragma unroll
    for (int off = 32; off; off >>= 1) {
        unsigned long long o = __shfl_down(key, off);
        if (o < key) key = o;
    }
    unsigned long long* kslot = (unsigned long long*)re;  // reuse LDS (pre-load)
    if (lane == 0) kslot[wave] = key;
    __syncthreads();
    unsigned long long kmin = kslot[0];
    #pragma unroll
    for (int w = 1; w < THREADS / 64; ++w) {
        unsigned long long o = kslot[w];
        if (o < kmin) kmin = o;
    }
    const int ri = (int)(kmin & 0xFFFFFFFFu);
    __syncthreads();   // all done reading kslot before re[] is overwritten

    // ---- Phase 1: load row as 8192 complex (even->re, odd->im), coalesced ----
    const float2* xr = (const float2*)(x + (size_t)row * NREAL);
    for (int n = tid; n < MHALF; n += THREADS) {
        float2 v = xr[n];
        re[n] = v.x; im[n] = v.y;
    }
    __syncthreads();

    // ---- Phase 2: in-place radix-2 DIF FFT, output bit-reversed ----
    const float NTWO_PI = -6.283185307179586f;
    int lh = 12;
    for (int stage = 0; stage < 13; ++stage, --lh) {
        const int half = 1 << lh;
        const float angscale = NTWO_PI / (float)(half << 1);
        for (int j = tid; j < MHALF / 2; j += THREADS) {
            const int pos = j & (half - 1);
            const int i0  = ((j >> lh) << (lh + 1)) + pos;
            const int i1  = i0 + half;
            float ar = re[i0], ai = im[i0];
            float cr = re[i1], ci = im[i1];
            float s_, c_;
            __sincosf(angscale * (float)pos, &s_, &c_);
            re[i0] = ar + cr; im[i0] = ai + ci;
            float tr = ar - cr, ti = ai - ci;
            re[i1] = tr * c_ - ti * s_;
            im[i1] = tr * s_ + ti * c_;
        }
        __syncthreads();
        // no race: butterfly (i0,i1) pairs partition the array within a stage
    }

    // ---- Phase 3: rfft untangle for k in [364,2276), P1, masked sum ----
    // X[k] = Xe + W^k * Xo, Xe = (Z[k]+conj(Z[M-k]))/2, Xo = (Z[k]-conj(Z[M-k]))/(2i)
    // 1/N^2 normalization cancels in pulse/other ratio -> skipped.
    float other = 0.0f;
    float mypulse = 0.0f;
    bool havepulse = false;
    for (int k = MIN_IDX + tid; k < MAX_IDX; k += THREADS) {
        int ia = br13(k);
        int ib = br13(MHALF - k);
        float zr = re[ia], zi = im[ia];
        float wr = re[ib], wi = im[ib];
        float xer  = 0.5f * (zr + wr), xei = 0.5f * (zi - wi);
        float xor_ = 0.5f * (zi + wi), xoi = -0.5f * (zr - wr);
        float s_, c_;
        __sincosf(NTWO_PI * (float)k * (1.0f / 16384.0f), &s_, &c_);
        float xr_ = xer + c_ * xor_ - s_ * xoi;
        float xi_ = xei + c_ * xoi + s_ * xor_;
        float p = xr_ * xr_ + xi_ * xi_;
        if (k < ri - 1 || k > ri + 1) other += p;   // mask: [364,ri-1) U [ri+2,2276)
        if (k == ri) { mypulse = p; havepulse = true; }
    }
    __syncthreads();           // all Z reads done; re/im reusable as scratch
    if (havepulse) im[0] = mypulse;   // exactly one writer (ri in [410,1776])
    #pragma unroll
    for (int off = 32; off; off >>= 1) other += __shfl_down(other, off);
    if (lane == 0) re[wave] = other;
    __syncthreads();
    if (tid == 0) {
        float tot = 0.0f;
        #pragma unroll
        for (int w = 0; w < THREADS / 64; ++w) tot += re[w];
        const float denom = (float)(MAX_IDX - MIN_IDX - 3);  // 1909
        float snr = 10.0f * log10f(im[0] * denom / tot);
        snr_out[row] = snr;
    }
}

__global__ void negsnr_mean_kernel(const float* __restrict__ snr,
                                   float* __restrict__ out, int n)
{
    __shared__ float sacc[4];
    const int tid = threadIdx.x;
    float acc = 0.0f;
    for (int i = tid; i < n; i += 256) acc += snr[i];
    #pragma unroll
    for (int off = 32; off; off >>= 1) acc += __shfl_down(acc, off);
    if ((tid & 63) == 0) sacc[tid >> 6] = acc;
    __syncthreads();
    if (tid == 0) {
        float t = sacc[0] + sacc[1] + sacc[2] + sacc[3];
        out[0] = -t / (float)n;
    }
}

extern "C" void kernel_launch(void* const* d_in, const int* in_sizes, int n_in,
                              void* d_out, int out_size, void* d_ws, size_t ws_size,
                              hipStream_t stream) {
    const float* outputs = (const float*)d_in[0];
    const float* targets = (const float*)d_in[1];
    const int B = in_sizes[1];                 // 1024 rows (targets count)
    float* snr = (float*)d_ws;                 // B floats of scratch

    negsnr_row_kernel<<<B, THREADS, 0, stream>>>(outputs, targets, snr);
    negsnr_mean_kernel<<<1, 256, 0, stream>>>(snr, (float*)d_out, B);
}

// Round 3
// 37.266 us; speedup vs baseline: 1.9723x; 1.9723x over previous
//
#include <hip/hip_runtime.h>
#include <math.h>

#define THREADS 512
#define MHALF 8192      // complex FFT length (N/2)
#define NREAL 16384
#define MIN_IDX 364     // argmin |f - 40/60|, exact fp32 (f[k]=k*15/8192 is exact)
#define MAX_IDX 2276    // argmin |f - 250/60|, exact fp32

__device__ __forceinline__ int br13(int x) {
    return (int)(__brev((unsigned)x) >> 19);
}

// LDS index swizzle: XOR bits 1..4 with bits 5..8. Involution, preserves bit 0,
// and PHI(i)+1 == PHI(i+1) for even i (float4-pair stays contiguous+aligned).
__device__ __forceinline__ int PHI(int i) {
    return i ^ (((i >> 5) & 15) << 1);
}

__device__ __forceinline__ float2 cmul(float2 a, float2 b) {
    return make_float2(a.x * b.x - a.y * b.y, a.x * b.y + a.y * b.x);
}

// DIF butterfly: (a,b) -> (a+b, (a-b)*tw)
__device__ __forceinline__ void bfly(float2& a, float2& b, float2 tw) {
    float2 t = make_float2(a.x - b.x, a.y - b.y);
    a.x += b.x; a.y += b.y;
    b = cmul(t, tw);
}

// Four radix-2 DIF stages on 16 regs. v[m] holds virtual position base+stride*m
// of a length-L sub-FFT (stride = L/16); W1 = exp(-2*pi*i*base/L).
__device__ __forceinline__ void fft_block16(float2 v[16], float2 W1)
{
    // C16[m] = exp(-2*pi*i*m/16) = exp(-i*pi*m/8)   (16th roots of unity)
    constexpr float C16x[8] = {1.f,  0.92387953251128674f,  0.70710678118654757f,  0.38268343236508978f,
                               0.f, -0.38268343236508978f, -0.70710678118654757f, -0.92387953251128674f};
    constexpr float C16y[8] = {0.f, -0.38268343236508978f, -0.70710678118654757f, -0.92387953251128674f,
                              -1.f, -0.92387953251128674f, -0.70710678118654757f, -0.38268343236508978f};
    // C8[m] = exp(-2*pi*i*m/8)
    constexpr float C8x[4] = {1.f,  0.70710678118654757f,  0.f, -0.70710678118654757f};
    constexpr float C8y[4] = {0.f, -0.70710678118654757f, -1.f, -0.70710678118654757f};

    float2 W2 = cmul(W1, W1), W4 = cmul(W2, W2), W8 = cmul(W4, W4);

    // stage A: pairs (m, m+8), tw = W1 * C16[m]
    #pragma unroll
    for (int m = 0; m < 8; ++m) {
        float2 tw = cmul(W1, make_float2(C16x[m], C16y[m]));
        bfly(v[m], v[m + 8], tw);
    }
    // stage B: pairs (idx, idx+4) in groups of 8, tw = W2 * C8[m]
    #pragma unroll
    for (int g = 0; g < 2; ++g) {
        #pragma unroll
        for (int m = 0; m < 4; ++m) {
            float2 tw = cmul(W2, make_float2(C8x[m], C8y[m]));
            bfly(v[8 * g + m], v[8 * g + m + 4], tw);
        }
    }
    // stage C: pairs (idx, idx+2) in groups of 4, tw = W4 * {1, -i}
    float2 W4i = make_float2(W4.y, -W4.x);
    #pragma unroll
    for (int g = 0; g < 4; ++g) {
        bfly(v[4 * g + 0], v[4 * g + 2], W4);
        bfly(v[4 * g + 1], v[4 * g + 3], W4i);
    }
    // stage D: pairs (2g, 2g+1), tw = W8
    #pragma unroll
    for (int g = 0; g < 8; ++g)
        bfly(v[2 * g], v[2 * g + 1], W8);
}

// One block per row. LDS: exactly 64 KiB -> 2 blocks/CU.
__global__ __launch_bounds__(THREADS, 2)
void negsnr_row_kernel(const float* __restrict__ x,
                       const float* __restrict__ targets,
                       float* __restrict__ snr_out)
{
    __shared__ float2 cf[MHALF];   // 65536 bytes (the full static-LDS budget)
    const int row  = blockIdx.x;
    const int tid  = threadIdx.x;
    const int lane = tid & 63;
    const int wave = tid >> 6;

    // ---- Phase 0: ref_idx, analytic (4 candidates), exact fp32 replication ----
    const float step = 15.0f / 8192.0f;            // exact in fp32
    const float t_hz = targets[row] / 60.0f;       // fp32 divide, same as reference
    const float c = t_hz * (8192.0f / 15.0f);
    int kf = (int)floorf(c);
    int ri = 0; float best = 1e30f;
    #pragma unroll
    for (int d = -1; d <= 2; ++d) {                // ascending k, strict < => first-index tie-break
        int k = min(max(kf + d, 0), 8192);
        float dist = fabsf((float)k * step - t_hz);
        if (dist < best) { best = dist; ri = k; }
    }

    const float NTWO_PI = -6.2831853071795865f;

    // ---- Block 1: global -> regs (stride 512), stages 0-3, regs -> LDS ----
    const float2* xr = (const float2*)(x + (size_t)row * NREAL);
    float2 v[16];
    #pragma unroll
    for (int m = 0; m < 16; ++m) v[m] = xr[tid + 512 * m];
    {
        float s_, c_;
        __sincosf(NTWO_PI * (float)tid * (1.0f / 8192.0f), &s_, &c_);
        fft_block16(v, make_float2(c_, s_));
    }
    #pragma unroll
    for (int m = 0; m < 16; ++m) cf[PHI(tid + 512 * m)] = v[m];
    __syncthreads();

    // ---- Block 2: stride 32 within 512-chunks, stages 4-7 ----
    const int low5 = tid & 31;
    const int base2 = low5 + ((tid >> 5) << 9);
    #pragma unroll
    for (int m = 0; m < 16; ++m) v[m] = cf[PHI(base2 + 32 * m)];
    {
        float s_, c_;
        __sincosf(NTWO_PI * (float)low5 * (1.0f / 512.0f), &s_, &c_);
        fft_block16(v, make_float2(c_, s_));
    }
    #pragma unroll
    for (int m = 0; m < 16; ++m) cf[PHI(base2 + 32 * m)] = v[m];
    __syncthreads();

    // ---- Block 3: stride 2, stages 8-11 (base twiddle is a constant per parity) ----
    const int p = tid & 1;
    const int base3 = p + ((tid >> 1) << 5);
    #pragma unroll
    for (int m = 0; m < 16; ++m) v[m] = cf[PHI(base3 + 2 * m)];
    {
        float2 U = p ? make_float2(0.98078528040323044f, -0.19509032201612825f)  // exp(-i*pi/16)
                     : make_float2(1.0f, 0.0f);
        fft_block16(v, U);
    }
    #pragma unroll
    for (int m = 0; m < 16; ++m) cf[PHI(base3 + 2 * m)] = v[m];
    __syncthreads();
    // LDS now holds Y = FFT through stage 11. Stage 12 has twiddle 1 and is folded below:
    // for even a: Z[a] = Y[a]+Y[a+1]; for odd b: Z[b] = Y[b-1]-Y[b]; X[k] = Z[br13(k)].

    // ---- Phase 3: rfft untangle for k in [364,2276), P1, masked sum ----
    float other = 0.0f, pulse = 0.0f;
    bool hasp = false;
    for (int k = MIN_IDX + tid; k < MAX_IDX; k += THREADS) {
        int a = br13(k);              // even (k < 4096)
        int b = br13(MHALF - k);      // odd  (8192-k >= 4096)
        float4 ya = *(const float4*)&cf[PHI(a)];       // Y[a], Y[a+1]
        float4 yb = *(const float4*)&cf[PHI(b - 1)];   // Y[b-1], Y[b]
        float Zr  = ya.x + ya.z, Zi  = ya.y + ya.w;    // Z[k]
        float Zmr = yb.x - yb.z, Zmi = yb.y - yb.w;    // Z[8192-k]
        // Xe = (Z + conj(Zm))/2 ; Xo = (Z - conj(Zm))/(2i); X = Xe + W_N^k * Xo
        float xer  = 0.5f * (Zr + Zmr), xei = 0.5f * (Zi - Zmi);
        float xor_ = 0.5f * (Zi + Zmi), xoi = -0.5f * (Zr - Zmr);
        float s_, c_;
        __sincosf(NTWO_PI * (float)k * (1.0f / 16384.0f), &s_, &c_);
        float xr_ = xer + c_ * xor_ - s_ * xoi;
        float xi_ = xei + c_ * xoi + s_ * xor_;
        float pw = xr_ * xr_ + xi_ * xi_;
        if (k < ri - 1 || k > ri + 1) other += pw;     // mask: [364,ri-1) U [ri+2,2276)
        if (k == ri) { pulse = pw; hasp = true; }
    }
    __syncthreads();                 // all cf reads done; reuse as reduction scratch
    if (hasp) cf[8].x = pulse;       // exactly one writer (ri in [409,1776])
    #pragma unroll
    for (int off = 32; off; off >>= 1) other += __shfl_down(other, off);
    if (lane == 0) cf[wave].x = other;
    __syncthreads();
    if (tid == 0) {
        float tot = 0.0f;
        #pragma unroll
        for (int w = 0; w < 8; ++w) tot += cf[w].x;
        const float denom = (float)(MAX_IDX - MIN_IDX - 3);   // 1909
        snr_out[row] = 10.0f * log10f(cf[8].x * denom / tot);
    }
}

__global__ void negsnr_mean_kernel(const float* __restrict__ snr,
                                   float* __restrict__ out, int n)
{
    __shared__ float sacc[4];
    const int tid = threadIdx.x;
    float acc = 0.0f;
    for (int i = tid; i < n; i += 256) acc += snr[i];
    #pragma unroll
    for (int off = 32; off; off >>= 1) acc += __shfl_down(acc, off);
    if ((tid & 63) == 0) sacc[tid >> 6] = acc;
    __syncthreads();
    if (tid == 0) {
        float t = sacc[0] + sacc[1] + sacc[2] + sacc[3];
        out[0] = -t / (float)n;
    }
}

extern "C" void kernel_launch(void* const* d_in, const int* in_sizes, int n_in,
                              void* d_out, int out_size, void* d_ws, size_t ws_size,
                              hipStream_t stream) {
    const float* outputs = (const float*)d_in[0];
    const float* targets = (const float*)d_in[1];
    const int B = in_sizes[1];                 // 1024 rows
    float* snr = (float*)d_ws;                 // B floats of scratch

    negsnr_row_kernel<<<B, THREADS, 0, stream>>>(outputs, targets, snr);
    negsnr_mean_kernel<<<1, 256, 0, stream>>>(snr, (float*)d_out, B);
}